// Round 1
// baseline (2094.692 us; speedup 1.0000x reference)
//
#include <hip/hip_runtime.h>

// Hough voting (PoseCNN-style). Shapes: label (B,H,W) i32; vertex (B,3C,H,W) f32;
// extents (C,3); meta (B,9); out (B,C,9) f32. B=2,C=22,H=480,W=640.

__global__ void vote_kernel(const int* __restrict__ label,
                            const float* __restrict__ vertex,
                            unsigned* __restrict__ acc,
                            unsigned* __restrict__ cnt,
                            float* __restrict__ zsum,
                            int C, int H, int W, int HW)
{
    int p = blockIdx.x * blockDim.x + threadIdx.x;
    int b = blockIdx.y;
    if (p >= HW) return;
    int lab = label[(size_t)b * HW + p];
    const float* vb = vertex + ((size_t)(b * 3 * C + 3 * lab)) * HW + p;
    float nx = vb[0];
    float ny = vb[(size_t)HW];
    float z  = vb[2 * (size_t)HW];
    int bc = b * C + lab;
    atomicAdd(&cnt[bc], 1u);
    atomicAdd(&zsum[bc], z);
    if (lab > 0) {
        // Match XLA f32 exactly: no FMA contraction, IEEE sqrt/div, RNE round.
        float nrm = __fsqrt_rn(__fadd_rn(__fmul_rn(nx, nx), __fmul_rn(ny, ny)));
        float inv = __fdiv_rn(1.0f, __fadd_rn(nrm, 1e-8f));
        float nxn = __fmul_rn(nx, inv);
        float nyn = __fmul_rn(ny, inv);
        float xs = (float)(p % W);
        float ys = (float)(p / W);
        unsigned* accbc = acc + (size_t)bc * HW;
        #pragma unroll
        for (int i = 1; i <= 32; ++i) {
            float t = (float)i * 4.0f;
            float fx = __fadd_rn(xs, __fmul_rn(nxn, t));
            float fy = __fadd_rn(ys, __fmul_rn(nyn, t));
            int px = (int)rintf(fx);   // round half to even, like jnp.round
            int py = (int)rintf(fy);
            if (px >= 0 && px < W && py >= 0 && py < H)
                atomicAdd(&accbc[py * W + px], 1u);
        }
    }
}

__global__ void argmax_kernel(const unsigned* __restrict__ acc,
                              unsigned long long* __restrict__ keys,
                              int HW)
{
    __shared__ unsigned long long sk[256];
    int pair = blockIdx.y;  // b*C + c
    const unsigned* a = acc + (size_t)pair * HW;
    unsigned long long best = 0;
    for (int i = blockIdx.x * blockDim.x + threadIdx.x; i < HW;
         i += gridDim.x * blockDim.x) {
        // key: max count first, then min index (invert index for max-reduce)
        unsigned long long k =
            ((unsigned long long)a[i] << 32) | (unsigned long long)(0xFFFFFFFFu - (unsigned)i);
        if (k > best) best = k;
    }
    sk[threadIdx.x] = best;
    __syncthreads();
    for (int s = 128; s > 0; s >>= 1) {
        if ((int)threadIdx.x < s) {
            if (sk[threadIdx.x + s] > sk[threadIdx.x]) sk[threadIdx.x] = sk[threadIdx.x + s];
        }
        __syncthreads();
    }
    if (threadIdx.x == 0) atomicMax(&keys[pair], sk[0]);
}

__global__ void finalize_kernel(const unsigned long long* __restrict__ keys,
                                const unsigned* __restrict__ cnt,
                                const float* __restrict__ zsum,
                                const float* __restrict__ extents,
                                const float* __restrict__ meta,
                                float* __restrict__ out,
                                int B, int C, int W)
{
    int i = threadIdx.x;
    if (i >= B * C) return;
    int b = i / C, c = i % C;
    unsigned long long k = keys[i];
    unsigned votes = (unsigned)(k >> 32);
    unsigned peak = 0xFFFFFFFFu - (unsigned)(k & 0xFFFFFFFFull);
    float cx = (float)(peak % (unsigned)W);
    float cy = (float)(peak / (unsigned)W);
    float n = (float)cnt[i];
    float depth = zsum[i] / fmaxf(n, 1.0f);
    float fx = meta[b * 9 + 0];
    const float* e = extents + c * 3;
    float diag = sqrtf(e[0] * e[0] + e[1] * e[1] + e[2] * e[2]);
    float half = 0.5f * diag * fx / fmaxf(fabsf(depth), 0.001f);
    float* o = out + (size_t)i * 9;
    o[0] = (float)c;
    o[1] = (float)votes;
    o[2] = cx - half;
    o[3] = cy - half;
    o[4] = cx + half;
    o[5] = cy + half;
    o[6] = cx;
    o[7] = cy;
    o[8] = depth;
}

extern "C" void kernel_launch(void* const* d_in, const int* in_sizes, int n_in,
                              void* d_out, int out_size, void* d_ws, size_t ws_size,
                              hipStream_t stream)
{
    const int* label    = (const int*)d_in[0];
    const float* vertex = (const float*)d_in[1];
    const float* extents= (const float*)d_in[2];
    const float* meta   = (const float*)d_in[3];
    // d_in[4] = gt (unused), d_in[5] = is_train (unused)

    int C = in_sizes[2] / 3;      // extents: C*3
    int B = in_sizes[3] / 9;      // meta: B*9
    int HW = in_sizes[0] / B;     // label: B*H*W
    const int W = 640;
    int H = HW / W;

    size_t accBytes  = (size_t)B * C * HW * sizeof(unsigned);
    size_t keysOff   = accBytes;                       // 8-aligned (accBytes % 8 == 0)
    size_t cntOff    = keysOff + (size_t)B * C * 8;
    size_t zsumOff   = cntOff + (size_t)B * C * 4;
    size_t totalBytes= zsumOff + (size_t)B * C * 4;

    unsigned* acc            = (unsigned*)d_ws;
    unsigned long long* keys = (unsigned long long*)((char*)d_ws + keysOff);
    unsigned* cnt            = (unsigned*)((char*)d_ws + cntOff);
    float* zsum              = (float*)((char*)d_ws + zsumOff);

    hipMemsetAsync(d_ws, 0, totalBytes, stream);

    dim3 vgrid((HW + 255) / 256, B);
    vote_kernel<<<vgrid, 256, 0, stream>>>(label, vertex, acc, cnt, zsum, C, H, W, HW);

    dim3 agrid(32, B * C);
    argmax_kernel<<<agrid, 256, 0, stream>>>(acc, keys, HW);

    finalize_kernel<<<1, 64, 0, stream>>>(keys, cnt, zsum, extents, meta,
                                          (float*)d_out, B, C, W);
}

// Round 2
// 673.996 us; speedup vs baseline: 3.1079x; 3.1079x over previous
//
#include <hip/hip_runtime.h>

// Hough voting (PoseCNN-style). Shapes: label (B,H,W) i32; vertex (B,3C,H,W) f32;
// extents (C,3); meta (B,9); out (B,C,9) f32. B=2,C=22,H=480,W=640.

__global__ void vote_kernel(const int* __restrict__ label,
                            const float* __restrict__ vertex,
                            unsigned* __restrict__ acc,
                            unsigned* __restrict__ cnt,
                            float* __restrict__ zsum,
                            int C, int H, int W, int HW)
{
    extern __shared__ char smem[];
    unsigned* s_cnt = (unsigned*)smem;          // C entries
    float*    s_z   = (float*)(smem + (size_t)C * 4);  // C entries

    int tid = threadIdx.x;
    for (int i = tid; i < C; i += blockDim.x) { s_cnt[i] = 0u; s_z[i] = 0.0f; }
    __syncthreads();

    int p = blockIdx.x * blockDim.x + tid;
    int b = blockIdx.y;
    bool valid = (p < HW);

    if (valid) {
        int lab = label[(size_t)b * HW + p];
        const float* vb = vertex + ((size_t)(b * 3 * C + 3 * lab)) * HW + p;
        float nx = vb[0];
        float ny = vb[(size_t)HW];
        float z  = vb[2 * (size_t)HW];

        // Block-local aggregation: LDS atomics, ~44 slots, low contention.
        atomicAdd(&s_cnt[lab], 1u);
        atomicAdd(&s_z[lab], z);

        if (lab > 0) {
            // Match XLA f32 exactly: no FMA contraction, IEEE sqrt/div, RNE round.
            float nrm = __fsqrt_rn(__fadd_rn(__fmul_rn(nx, nx), __fmul_rn(ny, ny)));
            float inv = __fdiv_rn(1.0f, __fadd_rn(nrm, 1e-8f));
            float nxn = __fmul_rn(nx, inv);
            float nyn = __fmul_rn(ny, inv);
            float xs = (float)(p % W);
            float ys = (float)(p / W);
            unsigned* accbc = acc + (size_t)(b * C + lab) * HW;
            #pragma unroll
            for (int i = 1; i <= 32; ++i) {
                float t = (float)i * 4.0f;
                float fx = __fadd_rn(xs, __fmul_rn(nxn, t));
                float fy = __fadd_rn(ys, __fmul_rn(nyn, t));
                int px = (int)rintf(fx);   // round half to even, like jnp.round
                int py = (int)rintf(fy);
                if (px >= 0 && px < W && py >= 0 && py < H)
                    atomicAdd(&accbc[py * W + px], 1u);
            }
        }
    }

    __syncthreads();
    // One global atomic per class per block.
    for (int i = tid; i < C; i += blockDim.x) {
        unsigned c = s_cnt[i];
        if (c) {
            atomicAdd(&cnt[b * C + i], c);
            atomicAdd(&zsum[b * C + i], s_z[i]);
        }
    }
}

__global__ void argmax_kernel(const unsigned* __restrict__ acc,
                              unsigned long long* __restrict__ keys,
                              int HW)
{
    __shared__ unsigned long long sk[256];
    int pair = blockIdx.y;  // b*C + c
    const unsigned* a = acc + (size_t)pair * HW;
    unsigned long long best = 0;
    for (int i = blockIdx.x * blockDim.x + threadIdx.x; i < HW;
         i += gridDim.x * blockDim.x) {
        // key: max count first, then min index (invert index for max-reduce)
        unsigned long long k =
            ((unsigned long long)a[i] << 32) | (unsigned long long)(0xFFFFFFFFu - (unsigned)i);
        if (k > best) best = k;
    }
    sk[threadIdx.x] = best;
    __syncthreads();
    for (int s = 128; s > 0; s >>= 1) {
        if ((int)threadIdx.x < s) {
            if (sk[threadIdx.x + s] > sk[threadIdx.x]) sk[threadIdx.x] = sk[threadIdx.x + s];
        }
        __syncthreads();
    }
    if (threadIdx.x == 0) atomicMax(&keys[pair], sk[0]);
}

__global__ void finalize_kernel(const unsigned long long* __restrict__ keys,
                                const unsigned* __restrict__ cnt,
                                const float* __restrict__ zsum,
                                const float* __restrict__ extents,
                                const float* __restrict__ meta,
                                float* __restrict__ out,
                                int B, int C, int W)
{
    int i = threadIdx.x;
    if (i >= B * C) return;
    int b = i / C, c = i % C;
    unsigned long long k = keys[i];
    unsigned votes = (unsigned)(k >> 32);
    unsigned peak = 0xFFFFFFFFu - (unsigned)(k & 0xFFFFFFFFull);
    float cx = (float)(peak % (unsigned)W);
    float cy = (float)(peak / (unsigned)W);
    float n = (float)cnt[i];
    float depth = zsum[i] / fmaxf(n, 1.0f);
    float fx = meta[b * 9 + 0];
    const float* e = extents + c * 3;
    float diag = sqrtf(e[0] * e[0] + e[1] * e[1] + e[2] * e[2]);
    float half = 0.5f * diag * fx / fmaxf(fabsf(depth), 0.001f);
    float* o = out + (size_t)i * 9;
    o[0] = (float)c;
    o[1] = (float)votes;
    o[2] = cx - half;
    o[3] = cy - half;
    o[4] = cx + half;
    o[5] = cy + half;
    o[6] = cx;
    o[7] = cy;
    o[8] = depth;
}

extern "C" void kernel_launch(void* const* d_in, const int* in_sizes, int n_in,
                              void* d_out, int out_size, void* d_ws, size_t ws_size,
                              hipStream_t stream)
{
    const int* label    = (const int*)d_in[0];
    const float* vertex = (const float*)d_in[1];
    const float* extents= (const float*)d_in[2];
    const float* meta   = (const float*)d_in[3];
    // d_in[4] = gt (unused), d_in[5] = is_train (unused)

    int C = in_sizes[2] / 3;      // extents: C*3
    int B = in_sizes[3] / 9;      // meta: B*9
    int HW = in_sizes[0] / B;     // label: B*H*W
    const int W = 640;
    int H = HW / W;

    size_t accBytes  = (size_t)B * C * HW * sizeof(unsigned);
    size_t keysOff   = accBytes;                       // 8-aligned (accBytes % 8 == 0)
    size_t cntOff    = keysOff + (size_t)B * C * 8;
    size_t zsumOff   = cntOff + (size_t)B * C * 4;
    size_t totalBytes= zsumOff + (size_t)B * C * 4;

    unsigned* acc            = (unsigned*)d_ws;
    unsigned long long* keys = (unsigned long long*)((char*)d_ws + keysOff);
    unsigned* cnt            = (unsigned*)((char*)d_ws + cntOff);
    float* zsum              = (float*)((char*)d_ws + zsumOff);

    hipMemsetAsync(d_ws, 0, totalBytes, stream);

    dim3 vgrid((HW + 255) / 256, B);
    size_t smem = (size_t)C * 8;
    vote_kernel<<<vgrid, 256, smem, stream>>>(label, vertex, acc, cnt, zsum, C, H, W, HW);

    dim3 agrid(32, B * C);
    argmax_kernel<<<agrid, 256, 0, stream>>>(acc, keys, HW);

    finalize_kernel<<<1, 64, 0, stream>>>(keys, cnt, zsum, extents, meta,
                                          (float*)d_out, B, C, W);
}

// Round 3
// 405.857 us; speedup vs baseline: 5.1612x; 1.6607x over previous
//
#include <hip/hip_runtime.h>

// Hough voting (PoseCNN-style), two-phase binned version.
// label (B,H,W) i32; vertex (B,3C,H,W) f32; extents (C,3); meta (B,9);
// out (B,C,9) f32. B=2,C=22,H=480,W=640.
//
// Phase 1 (emit): per 512-pixel block, compute up to 16384 ray votes, bin them
// by destination row py in LDS, flush each row with one global cursor atomic +
// coalesced u16 records (class<<10 | px). Replaces 18.8M scattered global
// atomics (32B memory-side transaction each) with ~600K coalesced bursts.
// Phase 2 (hist): one block per (b,py): exact C*W histogram in LDS, then scan
// ALL cells (zero-count included -> tie-break identical to jnp.argmax) and
// atomicMax a (count<<32 | ~flat) key per (b,c).

#define MAXC 32  // label classes < 32 (C=22 here)

__global__ __launch_bounds__(512) void emit_kernel(
    const int* __restrict__ label, const float* __restrict__ vertex,
    unsigned short* __restrict__ bucketData, unsigned* __restrict__ cursor,
    unsigned* __restrict__ cnt, float* __restrict__ zsum,
    int C, int H, int W, int HW, int CAP)
{
    __shared__ unsigned s_bin[512];        // votes per destination row (H<=512)
    __shared__ unsigned s_scan[512];       // inclusive scan of s_bin
    __shared__ unsigned s_pos[512];        // running write positions
    __shared__ unsigned short s_buf[16384];// binned records, grouped by row
    __shared__ unsigned s_ccnt[MAXC];
    __shared__ float s_cz[MAXC];

    int tid = threadIdx.x;
    int b = blockIdx.y;
    int p = blockIdx.x * 512 + tid;

    s_bin[tid] = 0;
    if (tid < MAXC) { s_ccnt[tid] = 0u; s_cz[tid] = 0.0f; }
    __syncthreads();

    int lab = 0; float nxn = 0.f, nyn = 0.f, xs = 0.f, ys = 0.f; bool fg = false;
    if (p < HW) {
        lab = label[(size_t)b * HW + p];
        const float* vb = vertex + ((size_t)(b * 3 * C + 3 * lab)) * HW + p;
        float nx = vb[0];
        float ny = vb[(size_t)HW];
        float z  = vb[2 * (size_t)HW];
        atomicAdd(&s_ccnt[lab], 1u);
        atomicAdd(&s_cz[lab], z);
        if (lab > 0) {
            // Match XLA f32 exactly: no FMA contraction, IEEE sqrt/div, RNE round.
            float nrm = __fsqrt_rn(__fadd_rn(__fmul_rn(nx, nx), __fmul_rn(ny, ny)));
            float inv = __fdiv_rn(1.0f, __fadd_rn(nrm, 1e-8f));
            nxn = __fmul_rn(nx, inv);
            nyn = __fmul_rn(ny, inv);
            xs = (float)(p % W);
            ys = (float)(p / W);
            fg = true;
        }
    }

    // Pass A: count votes per destination row.
    if (fg) {
        #pragma unroll
        for (int i = 1; i <= 32; ++i) {
            float t = (float)i * 4.0f;
            int px = (int)rintf(__fadd_rn(xs, __fmul_rn(nxn, t)));
            int py = (int)rintf(__fadd_rn(ys, __fmul_rn(nyn, t)));
            if (px >= 0 && px < W && py >= 0 && py < H)
                atomicAdd(&s_bin[py], 1u);
        }
    }
    __syncthreads();

    // Inclusive scan over 512 bins (Hillis-Steele).
    unsigned own = s_bin[tid];
    s_scan[tid] = own;
    __syncthreads();
    for (int off = 1; off < 512; off <<= 1) {
        unsigned v = 0;
        if (tid >= off) v = s_scan[tid - off];
        __syncthreads();
        if (tid >= off) s_scan[tid] += v;
        __syncthreads();
    }
    s_pos[tid] = s_scan[tid] - own;  // exclusive base
    __syncthreads();

    // Pass B: scatter records into row-grouped LDS buffer.
    if (fg) {
        #pragma unroll
        for (int i = 1; i <= 32; ++i) {
            float t = (float)i * 4.0f;
            int px = (int)rintf(__fadd_rn(xs, __fmul_rn(nxn, t)));
            int py = (int)rintf(__fadd_rn(ys, __fmul_rn(nyn, t)));
            if (px >= 0 && px < W && py >= 0 && py < H) {
                unsigned slot = atomicAdd(&s_pos[py], 1u);
                s_buf[slot] = (unsigned short)((lab << 10) | px);
            }
        }
    }
    __syncthreads();

    // Flush: each wave handles rows wave, wave+8, ... One cursor atomic per
    // non-empty row, then a coalesced u16 burst.
    int wave = tid >> 6, lane = tid & 63;
    for (int y = wave; y < H; y += 8) {
        unsigned n = s_bin[y];
        if (!n) continue;
        unsigned ebase = s_scan[y] - n;
        unsigned gbase = 0;
        if (lane == 0) gbase = atomicAdd(&cursor[b * H + y], n);
        gbase = (unsigned)__shfl((int)gbase, 0, 64);
        unsigned short* dst = bucketData + (size_t)(b * H + y) * CAP;
        for (unsigned i = lane; i < n; i += 64) {
            unsigned g = gbase + i;
            if (g < (unsigned)CAP) dst[g] = s_buf[ebase + i];
        }
    }

    __syncthreads();
    if (tid < C) {
        unsigned c = s_ccnt[tid];
        if (c) {
            atomicAdd(&cnt[b * C + tid], c);
            atomicAdd(&zsum[b * C + tid], s_cz[tid]);
        }
    }
}

__global__ __launch_bounds__(256) void hist_kernel(
    const unsigned short* __restrict__ bucketData,
    const unsigned* __restrict__ cursor,
    unsigned long long* __restrict__ keys,
    int C, int H, int W, int CAP)
{
    extern __shared__ char sm[];
    unsigned* hist = (unsigned*)sm;                                   // C*W
    unsigned long long* red = (unsigned long long*)(sm + (size_t)C * W * 4); // 256

    int tid = threadIdx.x;
    int py = blockIdx.x;
    int b = blockIdx.y;

    for (int i = tid; i < C * W; i += 256) hist[i] = 0u;
    __syncthreads();

    int bucket = b * H + py;
    unsigned n = cursor[bucket];
    if (n > (unsigned)CAP) n = (unsigned)CAP;
    const unsigned short* src = bucketData + (size_t)bucket * CAP;
    for (unsigned i = tid; i < n; i += 256) {
        unsigned r = src[i];
        unsigned c = r >> 10, px = r & 1023u;
        atomicAdd(&hist[c * W + px], 1u);
    }
    __syncthreads();

    // Per-class argmax over ALL cells of this row (zero counts included so
    // global tie-break == jnp.argmax: max count, then min flat index).
    for (int c = 0; c < C; ++c) {
        unsigned long long best = 0;
        for (int px = tid; px < W; px += 256) {
            unsigned cv = hist[c * W + px];
            unsigned flat = (unsigned)(py * W + px);
            unsigned long long k =
                ((unsigned long long)cv << 32) | (unsigned long long)(0xFFFFFFFFu - flat);
            if (k > best) best = k;
        }
        red[tid] = best;
        __syncthreads();
        for (int s = 128; s > 0; s >>= 1) {
            if (tid < s && red[tid + s] > red[tid]) red[tid] = red[tid + s];
            __syncthreads();
        }
        if (tid == 0) atomicMax(&keys[b * C + c], red[0]);
        __syncthreads();
    }
}

__global__ void finalize_kernel(const unsigned long long* __restrict__ keys,
                                const unsigned* __restrict__ cnt,
                                const float* __restrict__ zsum,
                                const float* __restrict__ extents,
                                const float* __restrict__ meta,
                                float* __restrict__ out,
                                int B, int C, int W)
{
    int i = threadIdx.x;
    if (i >= B * C) return;
    int b = i / C, c = i % C;
    unsigned long long k = keys[i];
    unsigned votes = (unsigned)(k >> 32);
    unsigned peak = 0xFFFFFFFFu - (unsigned)(k & 0xFFFFFFFFull);
    float cx = (float)(peak % (unsigned)W);
    float cy = (float)(peak / (unsigned)W);
    float n = (float)cnt[i];
    float depth = zsum[i] / fmaxf(n, 1.0f);
    float fx = meta[b * 9 + 0];
    const float* e = extents + c * 3;
    float diag = sqrtf(e[0] * e[0] + e[1] * e[1] + e[2] * e[2]);
    float half = 0.5f * diag * fx / fmaxf(fabsf(depth), 0.001f);
    float* o = out + (size_t)i * 9;
    o[0] = (float)c;
    o[1] = (float)votes;
    o[2] = cx - half;
    o[3] = cy - half;
    o[4] = cx + half;
    o[5] = cy + half;
    o[6] = cx;
    o[7] = cy;
    o[8] = depth;
}

extern "C" void kernel_launch(void* const* d_in, const int* in_sizes, int n_in,
                              void* d_out, int out_size, void* d_ws, size_t ws_size,
                              hipStream_t stream)
{
    const int* label    = (const int*)d_in[0];
    const float* vertex = (const float*)d_in[1];
    const float* extents= (const float*)d_in[2];
    const float* meta   = (const float*)d_in[3];
    // d_in[4] = gt (unused), d_in[5] = is_train (unused)

    int C = in_sizes[2] / 3;      // extents: C*3
    int B = in_sizes[3] / 9;      // meta: B*9
    int HW = in_sizes[0] / B;     // label: B*H*W
    const int W = 640;
    int H = HW / W;
    int NB = B * H;               // number of row buckets

    // Workspace layout: keys (u64) | cursor (u32) | cnt | zsum | pad | bucketData (u16)
    size_t keysOff = 0;
    size_t curOff  = keysOff + (size_t)B * C * 8;
    size_t cntOff  = curOff + (size_t)NB * 4;
    size_t zsumOff = cntOff + (size_t)B * C * 4;
    size_t zeroEnd = zsumOff + (size_t)B * C * 4;
    size_t dataOff = (zeroEnd + 63) & ~(size_t)63;

    // Adaptive bucket capacity (records are u16). Mean load ~19.6K/bucket.
    size_t availRec = (ws_size > dataOff) ? (ws_size - dataOff) / ((size_t)NB * 2) : 0;
    int CAP = (int)(availRec > 32768 ? 32768 : availRec);
    CAP &= ~63;

    unsigned long long* keys = (unsigned long long*)((char*)d_ws + keysOff);
    unsigned* cursor         = (unsigned*)((char*)d_ws + curOff);
    unsigned* cnt            = (unsigned*)((char*)d_ws + cntOff);
    float* zsum              = (float*)((char*)d_ws + zsumOff);
    unsigned short* bucketData = (unsigned short*)((char*)d_ws + dataOff);

    hipMemsetAsync(d_ws, 0, zeroEnd, stream);

    dim3 egrid((HW + 511) / 512, B);
    emit_kernel<<<egrid, 512, 0, stream>>>(label, vertex, bucketData, cursor,
                                           cnt, zsum, C, H, W, HW, CAP);

    dim3 hgrid(H, B);
    size_t hsm = (size_t)C * W * 4 + 256 * 8;
    hist_kernel<<<hgrid, 256, hsm, stream>>>(bucketData, cursor, keys, C, H, W, CAP);

    finalize_kernel<<<1, 64, 0, stream>>>(keys, cnt, zsum, extents, meta,
                                          (float*)d_out, B, C, W);
}

// Round 4
// 121.292 us; speedup vs baseline: 17.2698x; 3.3461x over previous
//
#include <hip/hip_runtime.h>

// Hough voting (PoseCNN-style), two-phase binned version, round 4.
// label (B,H,W) i32; vertex (B,3C,H,W) f32; extents (C,3); meta (B,9);
// out (B,C,9) f32. B=2,C=22,H=480,W=640. Assumes H <= 512, C < 32.
//
// Phase 1 (emit): per 512-pixel block: compute the 32 ray votes ONCE into
// registers, bin by destination row py in LDS (count -> shuffle-scan ->
// scatter), reserve global row cursors with ONE parallel atomic per row
// (thread t owns row t), then coalesced u16 record bursts (class<<10 | px).
// Phase 2 (hist): one block per (b,py): exact C*W histogram in LDS packed as
// u16 pairs, then scan ALL cells (zero-count included -> tie-break identical
// to jnp.argmax) with wave-shuffle reductions, atomicMax a
// (count<<32 | ~flat) key per (b,c).

#define MAXC 32

__global__ __launch_bounds__(512) void emit_kernel(
    const int* __restrict__ label, const float* __restrict__ vertex,
    unsigned short* __restrict__ bucketData, unsigned* __restrict__ cursor,
    unsigned* __restrict__ cnt, float* __restrict__ zsum,
    int C, int H, int W, int HW, int CAP)
{
    __shared__ unsigned s_bin[512];         // votes per destination row
    __shared__ unsigned s_pos[512];         // excl base -> (after pass B) incl end
    __shared__ unsigned s_gbase[512];       // global base per row
    __shared__ unsigned short s_buf[16384]; // binned records, grouped by row
    __shared__ unsigned s_wtot[8];
    __shared__ unsigned s_ccnt[MAXC];
    __shared__ float s_cz[MAXC];

    int tid = threadIdx.x;
    int lane = tid & 63, wave = tid >> 6;
    int b = blockIdx.y;
    int p = blockIdx.x * 512 + tid;

    s_bin[tid] = 0;
    if (tid < MAXC) { s_ccnt[tid] = 0u; s_cz[tid] = 0.0f; }
    __syncthreads();

    int lab = 0;
    unsigned vote[32];   // py<<10 | px, 0xFFFFFFFF = invalid (static idx only)
    bool fg = false;
    if (p < HW) {
        lab = label[(size_t)b * HW + p];
        const float* vb = vertex + ((size_t)(b * 3 * C + 3 * lab)) * HW + p;
        float nx = vb[0];
        float ny = vb[(size_t)HW];
        float z  = vb[2 * (size_t)HW];
        atomicAdd(&s_ccnt[lab], 1u);
        atomicAdd(&s_cz[lab], z);
        if (lab > 0) {
            fg = true;
            // Match XLA f32 exactly: no FMA contraction, IEEE sqrt/div, RNE round.
            float nrm = __fsqrt_rn(__fadd_rn(__fmul_rn(nx, nx), __fmul_rn(ny, ny)));
            float inv = __fdiv_rn(1.0f, __fadd_rn(nrm, 1e-8f));
            float nxn = __fmul_rn(nx, inv);
            float nyn = __fmul_rn(ny, inv);
            float xs = (float)(p % W);
            float ys = (float)(p / W);
            #pragma unroll
            for (int i = 1; i <= 32; ++i) {
                float t = (float)i * 4.0f;
                int px = (int)rintf(__fadd_rn(xs, __fmul_rn(nxn, t)));
                int py = (int)rintf(__fadd_rn(ys, __fmul_rn(nyn, t)));
                vote[i - 1] = (px >= 0 && px < W && py >= 0 && py < H)
                            ? ((unsigned)(py << 10) | (unsigned)px) : 0xFFFFFFFFu;
            }
        }
    }
    if (!fg) {
        #pragma unroll
        for (int i = 0; i < 32; ++i) vote[i] = 0xFFFFFFFFu;
    }

    // Pass A: count votes per destination row.
    #pragma unroll
    for (int i = 0; i < 32; ++i)
        if (vote[i] != 0xFFFFFFFFu) atomicAdd(&s_bin[vote[i] >> 10], 1u);
    __syncthreads();

    // Inclusive scan over 512 bins: wave shuffle scan + cross-wave offsets.
    unsigned own = s_bin[tid];
    unsigned v = own;
    #pragma unroll
    for (int off = 1; off < 64; off <<= 1) {
        unsigned u = __shfl_up(v, off, 64);
        if (lane >= off) v += u;
    }
    if (lane == 63) s_wtot[wave] = v;
    __syncthreads();
    if (tid == 0) {
        unsigned a = 0;
        #pragma unroll
        for (int w2 = 0; w2 < 8; ++w2) { unsigned t2 = s_wtot[w2]; s_wtot[w2] = a; a += t2; }
    }
    __syncthreads();
    s_pos[tid] = v + s_wtot[wave] - own;   // exclusive base
    __syncthreads();

    // Pass B: scatter records into row-grouped LDS buffer.
    #pragma unroll
    for (int i = 0; i < 32; ++i) {
        unsigned vt = vote[i];
        if (vt != 0xFFFFFFFFu) {
            unsigned slot = atomicAdd(&s_pos[vt >> 10], 1u);
            s_buf[slot] = (unsigned short)(((unsigned)lab << 10) | (vt & 1023u));
        }
    }
    __syncthreads();
    // s_pos[y] is now the INCLUSIVE scan (base + n).

    // Reserve global space: one parallel atomic per row (thread t owns row t).
    if (tid < H) {
        unsigned n = s_bin[tid];
        s_gbase[tid] = n ? atomicAdd(&cursor[b * H + tid], n) : 0u;
    }
    __syncthreads();

    // Coalesced copy-out: wave w handles rows w, w+8, ...
    for (int y = wave; y < H; y += 8) {
        unsigned n = s_bin[y];
        if (!n) continue;
        unsigned ebase = s_pos[y] - n;
        unsigned gbase = s_gbase[y];
        unsigned short* dst = bucketData + (size_t)(b * H + y) * CAP;
        for (unsigned i = (unsigned)lane; i < n; i += 64) {
            unsigned g = gbase + i;
            if (g < (unsigned)CAP) dst[g] = s_buf[ebase + i];
        }
    }

    // Class aggregates (s_ccnt/s_cz final since the first barrier).
    if (tid < C) {
        unsigned c = s_ccnt[tid];
        if (c) {
            atomicAdd(&cnt[b * C + tid], c);
            atomicAdd(&zsum[b * C + tid], s_cz[tid]);
        }
    }
}

__global__ __launch_bounds__(256) void hist_kernel(
    const unsigned short* __restrict__ bucketData,
    const unsigned* __restrict__ cursor,
    unsigned long long* __restrict__ keys,
    int C, int H, int W, int CAP)
{
    extern __shared__ char sm[];
    unsigned* hist = (unsigned*)sm;   // C*W/2 words, u16 pair per word
    unsigned long long* s_wb =
        (unsigned long long*)(sm + (size_t)(C * W / 2) * 4);  // C*4 wave bests

    int tid = threadIdx.x;
    int lane = tid & 63, wave = tid >> 6;
    int py = blockIdx.x;
    int b = blockIdx.y;
    int words = C * W / 2;

    for (int i = tid; i < words; i += 256) hist[i] = 0u;
    __syncthreads();

    int bucket = b * H + py;
    unsigned n = cursor[bucket];
    if (n > (unsigned)CAP) n = (unsigned)CAP;
    const unsigned short* src = bucketData + (size_t)bucket * CAP;
    for (unsigned i = tid; i < n; i += 256) {
        unsigned r = src[i];
        unsigned idx = (r >> 10) * (unsigned)W + (r & 1023u);  // c*W+px
        atomicAdd(&hist[idx >> 1], 1u << ((idx & 1u) * 16));   // packed u16; max <= CAP < 65536
    }
    __syncthreads();

    // Per-class argmax over ALL cells of this row (zero counts included so
    // global tie-break == jnp.argmax: max count, then min flat index).
    unsigned rowbase = (unsigned)py * (unsigned)W;
    for (int c = 0; c < C; ++c) {
        unsigned long long best = 0;
        for (int px = tid; px < W; px += 256) {
            unsigned cv = (hist[(unsigned)(c * W + px) >> 1] >> ((px & 1) * 16)) & 0xFFFFu;
            unsigned long long k = ((unsigned long long)cv << 32)
                                 | (unsigned long long)(0xFFFFFFFFu - (rowbase + px));
            if (k > best) best = k;
        }
        #pragma unroll
        for (int off = 32; off > 0; off >>= 1) {
            unsigned long long o = __shfl_xor(best, off, 64);
            if (o > best) best = o;
        }
        if (lane == 0) s_wb[c * 4 + wave] = best;
    }
    __syncthreads();
    if (tid < C) {
        unsigned long long m = s_wb[tid * 4];
        #pragma unroll
        for (int w2 = 1; w2 < 4; ++w2)
            if (s_wb[tid * 4 + w2] > m) m = s_wb[tid * 4 + w2];
        atomicMax(&keys[b * C + tid], m);
    }
}

__global__ void finalize_kernel(const unsigned long long* __restrict__ keys,
                                const unsigned* __restrict__ cnt,
                                const float* __restrict__ zsum,
                                const float* __restrict__ extents,
                                const float* __restrict__ meta,
                                float* __restrict__ out,
                                int B, int C, int W)
{
    int i = threadIdx.x;
    if (i >= B * C) return;
    int b = i / C, c = i % C;
    unsigned long long k = keys[i];
    unsigned votes = (unsigned)(k >> 32);
    unsigned peak = 0xFFFFFFFFu - (unsigned)(k & 0xFFFFFFFFull);
    float cx = (float)(peak % (unsigned)W);
    float cy = (float)(peak / (unsigned)W);
    float n = (float)cnt[i];
    float depth = zsum[i] / fmaxf(n, 1.0f);
    float fx = meta[b * 9 + 0];
    const float* e = extents + c * 3;
    float diag = sqrtf(e[0] * e[0] + e[1] * e[1] + e[2] * e[2]);
    float half = 0.5f * diag * fx / fmaxf(fabsf(depth), 0.001f);
    float* o = out + (size_t)i * 9;
    o[0] = (float)c;
    o[1] = (float)votes;
    o[2] = cx - half;
    o[3] = cy - half;
    o[4] = cx + half;
    o[5] = cy + half;
    o[6] = cx;
    o[7] = cy;
    o[8] = depth;
}

extern "C" void kernel_launch(void* const* d_in, const int* in_sizes, int n_in,
                              void* d_out, int out_size, void* d_ws, size_t ws_size,
                              hipStream_t stream)
{
    const int* label    = (const int*)d_in[0];
    const float* vertex = (const float*)d_in[1];
    const float* extents= (const float*)d_in[2];
    const float* meta   = (const float*)d_in[3];
    // d_in[4] = gt (unused), d_in[5] = is_train (unused)

    int C = in_sizes[2] / 3;      // extents: C*3
    int B = in_sizes[3] / 9;      // meta: B*9
    int HW = in_sizes[0] / B;     // label: B*H*W
    const int W = 640;
    int H = HW / W;
    int NB = B * H;               // number of row buckets

    // Workspace layout: keys (u64) | cursor (u32) | cnt | zsum | pad | bucketData (u16)
    size_t keysOff = 0;
    size_t curOff  = keysOff + (size_t)B * C * 8;
    size_t cntOff  = curOff + (size_t)NB * 4;
    size_t zsumOff = cntOff + (size_t)B * C * 4;
    size_t zeroEnd = zsumOff + (size_t)B * C * 4;
    size_t dataOff = (zeroEnd + 63) & ~(size_t)63;

    // Adaptive bucket capacity (records are u16). Mean load ~20K/bucket.
    size_t availRec = (ws_size > dataOff) ? (ws_size - dataOff) / ((size_t)NB * 2) : 0;
    int CAP = (int)(availRec > 32768 ? 32768 : availRec);
    CAP &= ~63;

    unsigned long long* keys = (unsigned long long*)((char*)d_ws + keysOff);
    unsigned* cursor         = (unsigned*)((char*)d_ws + curOff);
    unsigned* cnt            = (unsigned*)((char*)d_ws + cntOff);
    float* zsum              = (float*)((char*)d_ws + zsumOff);
    unsigned short* bucketData = (unsigned short*)((char*)d_ws + dataOff);

    hipMemsetAsync(d_ws, 0, zeroEnd, stream);

    dim3 egrid((HW + 511) / 512, B);
    emit_kernel<<<egrid, 512, 0, stream>>>(label, vertex, bucketData, cursor,
                                           cnt, zsum, C, H, W, HW, CAP);

    dim3 hgrid(H, B);
    size_t hsm = (size_t)(C * W / 2) * 4 + (size_t)C * 4 * 8;
    hist_kernel<<<hgrid, 256, hsm, stream>>>(bucketData, cursor, keys, C, H, W, CAP);

    finalize_kernel<<<1, 64, 0, stream>>>(keys, cnt, zsum, extents, meta,
                                          (float*)d_out, B, C, W);
}

// Round 5
// 120.298 us; speedup vs baseline: 17.4125x; 1.0083x over previous
//
#include <hip/hip_runtime.h>

// Hough voting (PoseCNN-style), two-phase binned version, round 5.
// label (B,H,W) i32; vertex (B,3C,H,W) f32; extents (C,3); meta (B,9);
// out (B,C,9) f32. B=2,C=22,H=480,W=640. Assumes H <= 512, C < 32.
//
// r5 change: labels are i.i.d. random per pixel, so gathering the 3 vertex
// components by label is a fully-scattered read (64 line-requests per wave,
// ~73% of fetched bytes wasted, latency-bound). Replace with a coalesced
// sweep over ALL 3C planes at the thread's own pixel + cndmask select:
// 13.7x more bytes but perfectly coalesced -> BW-bound (~162MB @ ~6TB/s).
// Also reserve global row cursors right after the scan so the device-scope
// atomic latency hides under the LDS scatter pass.

#define MAXC 32

__global__ __launch_bounds__(512) void emit_kernel(
    const int* __restrict__ label, const float* __restrict__ vertex,
    unsigned short* __restrict__ bucketData, unsigned* __restrict__ cursor,
    unsigned* __restrict__ cnt, float* __restrict__ zsum,
    int C, int H, int W, int HW, int CAP)
{
    __shared__ unsigned s_bin[512];         // votes per destination row
    __shared__ unsigned s_pos[512];         // excl base -> (after pass B) incl end
    __shared__ unsigned s_gbase[512];       // global base per row
    __shared__ unsigned short s_buf[16384]; // binned records, grouped by row
    __shared__ unsigned s_wtot[8];
    __shared__ unsigned s_ccnt[MAXC];
    __shared__ float s_cz[MAXC];

    int tid = threadIdx.x;
    int lane = tid & 63, wave = tid >> 6;
    int b = blockIdx.y;
    int p = blockIdx.x * 512 + tid;

    s_bin[tid] = 0;
    if (tid < MAXC) { s_ccnt[tid] = 0u; s_cz[tid] = 0.0f; }
    __syncthreads();

    int lab = 0;
    unsigned vote[32];   // py<<10 | px, 0xFFFFFFFF = invalid (static idx only)
    bool fg = false;
    if (p < HW) {
        lab = label[(size_t)b * HW + p];
        // Coalesced full-plane sweep instead of label-directed gather.
        const float* vbase = vertex + (size_t)b * 3 * C * HW + p;
        float nx = 0.f, ny = 0.f, z = 0.f;
        #pragma unroll 2
        for (int c = 0; c < C; ++c) {
            float v0 = vbase[(size_t)(3 * c + 0) * HW];
            float v1 = vbase[(size_t)(3 * c + 1) * HW];
            float v2 = vbase[(size_t)(3 * c + 2) * HW];
            if (lab == c) { nx = v0; ny = v1; z = v2; }
        }
        atomicAdd(&s_ccnt[lab], 1u);
        atomicAdd(&s_cz[lab], z);
        if (lab > 0) {
            fg = true;
            // Match XLA f32 exactly: no FMA contraction, IEEE sqrt/div, RNE round.
            float nrm = __fsqrt_rn(__fadd_rn(__fmul_rn(nx, nx), __fmul_rn(ny, ny)));
            float inv = __fdiv_rn(1.0f, __fadd_rn(nrm, 1e-8f));
            float nxn = __fmul_rn(nx, inv);
            float nyn = __fmul_rn(ny, inv);
            float xs = (float)(p % W);
            float ys = (float)(p / W);
            #pragma unroll
            for (int i = 1; i <= 32; ++i) {
                float t = (float)i * 4.0f;
                int px = (int)rintf(__fadd_rn(xs, __fmul_rn(nxn, t)));
                int py = (int)rintf(__fadd_rn(ys, __fmul_rn(nyn, t)));
                vote[i - 1] = (px >= 0 && px < W && py >= 0 && py < H)
                            ? ((unsigned)(py << 10) | (unsigned)px) : 0xFFFFFFFFu;
            }
        }
    }
    if (!fg) {
        #pragma unroll
        for (int i = 0; i < 32; ++i) vote[i] = 0xFFFFFFFFu;
    }

    // Pass A: count votes per destination row.
    #pragma unroll
    for (int i = 0; i < 32; ++i)
        if (vote[i] != 0xFFFFFFFFu) atomicAdd(&s_bin[vote[i] >> 10], 1u);
    __syncthreads();

    // Inclusive scan over 512 bins: wave shuffle scan + cross-wave offsets.
    unsigned own = s_bin[tid];
    unsigned v = own;
    #pragma unroll
    for (int off = 1; off < 64; off <<= 1) {
        unsigned u = __shfl_up(v, off, 64);
        if (lane >= off) v += u;
    }
    if (lane == 63) s_wtot[wave] = v;

    // Reserve global space early: one parallel atomic per row (thread t owns
    // row t); latency hides under the scan tail + pass B scatter.
    unsigned resN = (tid < H) ? s_bin[tid] : 0u;
    unsigned resBase = resN ? atomicAdd(&cursor[b * H + tid], resN) : 0u;

    __syncthreads();
    if (tid == 0) {
        unsigned a = 0;
        #pragma unroll
        for (int w2 = 0; w2 < 8; ++w2) { unsigned t2 = s_wtot[w2]; s_wtot[w2] = a; a += t2; }
    }
    if (tid < H) s_gbase[tid] = resBase;
    __syncthreads();
    s_pos[tid] = v + s_wtot[wave] - own;   // exclusive base
    __syncthreads();

    // Pass B: scatter records into row-grouped LDS buffer.
    #pragma unroll
    for (int i = 0; i < 32; ++i) {
        unsigned vt = vote[i];
        if (vt != 0xFFFFFFFFu) {
            unsigned slot = atomicAdd(&s_pos[vt >> 10], 1u);
            s_buf[slot] = (unsigned short)(((unsigned)lab << 10) | (vt & 1023u));
        }
    }
    __syncthreads();
    // s_pos[y] is now the INCLUSIVE scan (base + n).

    // Coalesced copy-out: wave w handles rows w, w+8, ...
    for (int y = wave; y < H; y += 8) {
        unsigned n = s_bin[y];
        if (!n) continue;
        unsigned ebase = s_pos[y] - n;
        unsigned gbase = s_gbase[y];
        unsigned short* dst = bucketData + (size_t)(b * H + y) * CAP;
        for (unsigned i = (unsigned)lane; i < n; i += 64) {
            unsigned g = gbase + i;
            if (g < (unsigned)CAP) dst[g] = s_buf[ebase + i];
        }
    }

    // Class aggregates (s_ccnt/s_cz final since the first barrier after load).
    if (tid < C) {
        unsigned c = s_ccnt[tid];
        if (c) {
            atomicAdd(&cnt[b * C + tid], c);
            atomicAdd(&zsum[b * C + tid], s_cz[tid]);
        }
    }
}

__global__ __launch_bounds__(256) void hist_kernel(
    const unsigned short* __restrict__ bucketData,
    const unsigned* __restrict__ cursor,
    unsigned long long* __restrict__ keys,
    int C, int H, int W, int CAP)
{
    extern __shared__ char sm[];
    unsigned* hist = (unsigned*)sm;   // C*W/2 words, u16 pair per word
    unsigned long long* s_wb =
        (unsigned long long*)(sm + (size_t)(C * W / 2) * 4);  // C*4 wave bests

    int tid = threadIdx.x;
    int lane = tid & 63, wave = tid >> 6;
    int py = blockIdx.x;
    int b = blockIdx.y;
    int words = C * W / 2;

    for (int i = tid; i < words; i += 256) hist[i] = 0u;
    __syncthreads();

    int bucket = b * H + py;
    unsigned n = cursor[bucket];
    if (n > (unsigned)CAP) n = (unsigned)CAP;
    const unsigned short* src = bucketData + (size_t)bucket * CAP;
    for (unsigned i = tid; i < n; i += 256) {
        unsigned r = src[i];
        unsigned idx = (r >> 10) * (unsigned)W + (r & 1023u);  // c*W+px
        atomicAdd(&hist[idx >> 1], 1u << ((idx & 1u) * 16));   // packed u16; max <= CAP < 65536
    }
    __syncthreads();

    // Per-class argmax over ALL cells of this row (zero counts included so
    // global tie-break == jnp.argmax: max count, then min flat index).
    unsigned rowbase = (unsigned)py * (unsigned)W;
    for (int c = 0; c < C; ++c) {
        unsigned long long best = 0;
        for (int px = tid; px < W; px += 256) {
            unsigned cv = (hist[(unsigned)(c * W + px) >> 1] >> ((px & 1) * 16)) & 0xFFFFu;
            unsigned long long k = ((unsigned long long)cv << 32)
                                 | (unsigned long long)(0xFFFFFFFFu - (rowbase + px));
            if (k > best) best = k;
        }
        #pragma unroll
        for (int off = 32; off > 0; off >>= 1) {
            unsigned long long o = __shfl_xor(best, off, 64);
            if (o > best) best = o;
        }
        if (lane == 0) s_wb[c * 4 + wave] = best;
    }
    __syncthreads();
    if (tid < C) {
        unsigned long long m = s_wb[tid * 4];
        #pragma unroll
        for (int w2 = 1; w2 < 4; ++w2)
            if (s_wb[tid * 4 + w2] > m) m = s_wb[tid * 4 + w2];
        atomicMax(&keys[b * C + tid], m);
    }
}

__global__ void finalize_kernel(const unsigned long long* __restrict__ keys,
                                const unsigned* __restrict__ cnt,
                                const float* __restrict__ zsum,
                                const float* __restrict__ extents,
                                const float* __restrict__ meta,
                                float* __restrict__ out,
                                int B, int C, int W)
{
    int i = threadIdx.x;
    if (i >= B * C) return;
    int b = i / C, c = i % C;
    unsigned long long k = keys[i];
    unsigned votes = (unsigned)(k >> 32);
    unsigned peak = 0xFFFFFFFFu - (unsigned)(k & 0xFFFFFFFFull);
    float cx = (float)(peak % (unsigned)W);
    float cy = (float)(peak / (unsigned)W);
    float n = (float)cnt[i];
    float depth = zsum[i] / fmaxf(n, 1.0f);
    float fx = meta[b * 9 + 0];
    const float* e = extents + c * 3;
    float diag = sqrtf(e[0] * e[0] + e[1] * e[1] + e[2] * e[2]);
    float half = 0.5f * diag * fx / fmaxf(fabsf(depth), 0.001f);
    float* o = out + (size_t)i * 9;
    o[0] = (float)c;
    o[1] = (float)votes;
    o[2] = cx - half;
    o[3] = cy - half;
    o[4] = cx + half;
    o[5] = cy + half;
    o[6] = cx;
    o[7] = cy;
    o[8] = depth;
}

extern "C" void kernel_launch(void* const* d_in, const int* in_sizes, int n_in,
                              void* d_out, int out_size, void* d_ws, size_t ws_size,
                              hipStream_t stream)
{
    const int* label    = (const int*)d_in[0];
    const float* vertex = (const float*)d_in[1];
    const float* extents= (const float*)d_in[2];
    const float* meta   = (const float*)d_in[3];
    // d_in[4] = gt (unused), d_in[5] = is_train (unused)

    int C = in_sizes[2] / 3;      // extents: C*3
    int B = in_sizes[3] / 9;      // meta: B*9
    int HW = in_sizes[0] / B;     // label: B*H*W
    const int W = 640;
    int H = HW / W;
    int NB = B * H;               // number of row buckets

    // Workspace layout: keys (u64) | cursor (u32) | cnt | zsum | pad | bucketData (u16)
    size_t keysOff = 0;
    size_t curOff  = keysOff + (size_t)B * C * 8;
    size_t cntOff  = curOff + (size_t)NB * 4;
    size_t zsumOff = cntOff + (size_t)B * C * 4;
    size_t zeroEnd = zsumOff + (size_t)B * C * 4;
    size_t dataOff = (zeroEnd + 63) & ~(size_t)63;

    // Adaptive bucket capacity (records are u16). Mean load ~20K/bucket.
    size_t availRec = (ws_size > dataOff) ? (ws_size - dataOff) / ((size_t)NB * 2) : 0;
    int CAP = (int)(availRec > 32768 ? 32768 : availRec);
    CAP &= ~63;

    unsigned long long* keys = (unsigned long long*)((char*)d_ws + keysOff);
    unsigned* cursor         = (unsigned*)((char*)d_ws + curOff);
    unsigned* cnt            = (unsigned*)((char*)d_ws + cntOff);
    float* zsum              = (float*)((char*)d_ws + zsumOff);
    unsigned short* bucketData = (unsigned short*)((char*)d_ws + dataOff);

    hipMemsetAsync(d_ws, 0, zeroEnd, stream);

    dim3 egrid((HW + 511) / 512, B);
    emit_kernel<<<egrid, 512, 0, stream>>>(label, vertex, bucketData, cursor,
                                           cnt, zsum, C, H, W, HW, CAP);

    dim3 hgrid(H, B);
    size_t hsm = (size_t)(C * W / 2) * 4 + (size_t)C * 4 * 8;
    hist_kernel<<<hgrid, 256, hsm, stream>>>(bucketData, cursor, keys, C, H, W, CAP);

    finalize_kernel<<<1, 64, 0, stream>>>(keys, cnt, zsum, extents, meta,
                                          (float*)d_out, B, C, W);
}